// Round 1
// baseline (892.594 us; speedup 1.0000x reference)
//
#include <hip/hip_runtime.h>
#include <hip/hip_bf16.h>

#define DIM 256
#define KNB 32
#define NSITES 20000   // B*N = 4*5000
#define LDA 264        // padded row (bf16 elems): 528 B = 33*16, breaks bank conflicts

typedef __attribute__((ext_vector_type(8))) __bf16 bf16x8;
typedef __attribute__((ext_vector_type(4))) float floatx4;
typedef __attribute__((ext_vector_type(4))) unsigned short ushortx4;

union F8 { bf16x8 v; unsigned short u[8]; };

// fp32 -> bf16 round-to-nearest-even (inputs are finite; no NaN handling needed)
__device__ __forceinline__ unsigned short f2bf(float x) {
    unsigned u = __builtin_bit_cast(unsigned, x);
    u += 0x7fffu + ((u >> 16) & 1u);
    return (unsigned short)(u >> 16);
}

// ---------------------------------------------------------------------------
// Kernel 1: V3[s,o] = sum_d fi[s,d]*(W1-W2)[o,d] + b1[o] + b2[o]  -> d_out
// A rows (sites) and W rows are d-contiguous: direct global fragment loads.
// Block = 256 thr (4 waves) = 64 sites; wave w covers o-tiles 4w..4w+3.
// ---------------------------------------------------------------------------
__global__ __launch_bounds__(256, 2) void v3_kernel(
    const float* __restrict__ fi, const float* __restrict__ w1,
    const float* __restrict__ b1, const float* __restrict__ w2,
    const float* __restrict__ b2, float* __restrict__ out)
{
    const int tid  = threadIdx.x;
    const int w    = tid >> 6, lane = tid & 63;
    const int col  = lane & 15, quad = lane >> 4;
    const int sbase = blockIdx.x * 64;

    F8 w3f[4][8];
    float bias[4];
#pragma unroll
    for (int ot = 0; ot < 4; ++ot) {
        const int o = (4 * w + ot) * 16 + col;
        bias[ot] = b1[o] + b2[o];
        const float* p1 = w1 + o * DIM;
        const float* p2 = w2 + o * DIM;
#pragma unroll
        for (int c = 0; c < 8; ++c) {
            const int d0 = c * 32 + quad * 8;
            floatx4 a0 = *(const floatx4*)(p1 + d0);
            floatx4 a1 = *(const floatx4*)(p1 + d0 + 4);
            floatx4 s0 = *(const floatx4*)(p2 + d0);
            floatx4 s1 = *(const floatx4*)(p2 + d0 + 4);
#pragma unroll
            for (int j = 0; j < 4; ++j) {
                w3f[ot][c].u[j]     = f2bf(a0[j] - s0[j]);
                w3f[ot][c].u[j + 4] = f2bf(a1[j] - s1[j]);
            }
        }
    }

#pragma unroll 1
    for (int mt = 0; mt < 4; ++mt) {
        const int srow = sbase + mt * 16;
        if (srow >= NSITES) break;           // 20000 = 16*1250, tiles always full
        F8 a[8];
        const float* pa = fi + (size_t)(srow + col) * DIM;
#pragma unroll
        for (int c = 0; c < 8; ++c) {
            const int d0 = c * 32 + quad * 8;
            floatx4 f0 = *(const floatx4*)(pa + d0);
            floatx4 f1 = *(const floatx4*)(pa + d0 + 4);
#pragma unroll
            for (int j = 0; j < 4; ++j) {
                a[c].u[j]     = f2bf(f0[j]);
                a[c].u[j + 4] = f2bf(f1[j]);
            }
        }
#pragma unroll
        for (int ot = 0; ot < 4; ++ot) {
            floatx4 acc = {0.f, 0.f, 0.f, 0.f};
#pragma unroll
            for (int c = 0; c < 8; ++c)
                acc = __builtin_amdgcn_mfma_f32_16x16x32_bf16(a[c].v, w3f[ot][c].v, acc, 0, 0, 0);
            const int o = (4 * w + ot) * 16 + col;
#pragma unroll
            for (int r = 0; r < 4; ++r) {
                const int site = srow + quad * 4 + r;   // C/D: row = quad*4 + reg
                out[(size_t)site * DIM + o] = acc[r] + bias[ot];
            }
        }
    }
}

// ---------------------------------------------------------------------------
// Kernel 2: per site s: Y[k,o] = sum_d fj[s,d,k]*W2[o,d];
//           out[s,o] = relu(max_k Y[k,o] + V3[s,o])    (V3 read from d_out)
// Block = 512 thr (8 waves), wave w covers o-tiles 2w,2w+1; W2 frags in regs.
// f_j staged fp32->bf16 transposed [k][d] into double-buffered LDS.
// ---------------------------------------------------------------------------
__global__ __launch_bounds__(512, 2) void edge_kernel(
    const float* __restrict__ fj, const float* __restrict__ w2,
    float* __restrict__ out)
{
    __shared__ unsigned short As[2][KNB * LDA];   // 2 * 16.5 KB

    const int tid  = threadIdx.x;
    const int w    = tid >> 6, lane = tid & 63;
    const int col  = lane & 15, quad = lane >> 4;
    // staging mapping: thread covers d in [db,db+4), k in [4kg,4kg+4)
    const int kg = tid & 7, dg = tid >> 3, db = dg * 4;

    // W2 B-fragments: lane holds W2[o = 32w+16ot+col][d0..d0+7], d0 = 32c+8*quad
    F8 w2f[2][8];
#pragma unroll
    for (int ot = 0; ot < 2; ++ot) {
        const int o = 32 * w + ot * 16 + col;
        const float* p = w2 + o * DIM;
#pragma unroll
        for (int c = 0; c < 8; ++c) {
            const int d0 = c * 32 + quad * 8;
            floatx4 f0 = *(const floatx4*)(p + d0);
            floatx4 f1 = *(const floatx4*)(p + d0 + 4);
#pragma unroll
            for (int j = 0; j < 4; ++j) {
                w2f[ot][c].u[j]     = f2bf(f0[j]);
                w2f[ot][c].u[j + 4] = f2bf(f1[j]);
            }
        }
    }

    const int G = gridDim.x;
    floatx4 r[4];
    auto load_r = [&](int ss) {
        const float* p = fj + (size_t)ss * (DIM * KNB) + (db * KNB + kg * 4);
#pragma unroll
        for (int j = 0; j < 4; ++j)
            r[j] = *(const floatx4*)(p + j * KNB);   // 1 KB/wave coalesced
    };

    int s = blockIdx.x;
    load_r(s);
    int buf = 0;
    for (;;) {
        // cvt + transposed LDS write: As[k][d] = bf16(fj[s][d][k])
#pragma unroll
        for (int kk = 0; kk < 4; ++kk) {
            ushortx4 v;
#pragma unroll
            for (int j = 0; j < 4; ++j) v[j] = f2bf(r[j][kk]);
            *(ushortx4*)&As[buf][(4 * kg + kk) * LDA + db] = v;
        }
        __syncthreads();   // one barrier per site (drains writes)

        const int sn = s + G;
        if (sn < NSITES) load_r(sn);                 // prefetch overlaps MFMA
        const int oidx = s * DIM + 32 * w + (lane & 31);
        float v3 = 0.f;
        if (lane < 32) v3 = out[oidx];               // V3 from kernel 1

        floatx4 acc[2][2];
#pragma unroll
        for (int mt = 0; mt < 2; ++mt)
#pragma unroll
            for (int ot = 0; ot < 2; ++ot) acc[mt][ot] = (floatx4){0.f, 0.f, 0.f, 0.f};

#pragma unroll
        for (int mt = 0; mt < 2; ++mt) {
            F8 a[8];
#pragma unroll
            for (int c = 0; c < 8; ++c)   // A frag: lane = neighbor mt*16+col, 8 consec d
                a[c].v = *(const bf16x8*)&As[buf][(mt * 16 + col) * LDA + c * 32 + quad * 8];
#pragma unroll
            for (int ot = 0; ot < 2; ++ot)
#pragma unroll
                for (int c = 0; c < 8; ++c)
                    acc[mt][ot] = __builtin_amdgcn_mfma_f32_16x16x32_bf16(
                        a[c].v, w2f[ot][c].v, acc[mt][ot], 0, 0, 0);
        }

        // max over 32 neighbors: 8 in-lane regs + quad groups (xor 16, 32)
        float mv[2];
#pragma unroll
        for (int ot = 0; ot < 2; ++ot) {
            float m = fmaxf(
                fmaxf(fmaxf(acc[0][ot][0], acc[0][ot][1]), fmaxf(acc[0][ot][2], acc[0][ot][3])),
                fmaxf(fmaxf(acc[1][ot][0], acc[1][ot][1]), fmaxf(acc[1][ot][2], acc[1][ot][3])));
            m = fmaxf(m, __shfl_xor(m, 16));
            m = fmaxf(m, __shfl_xor(m, 32));
            mv[ot] = m;
        }
        if (lane < 32) {
            const float mm = (quad & 1) ? mv[1] : mv[0];
            out[oidx] = fmaxf(v3 + mm, 0.f);
        }

        if (sn >= NSITES) break;
        s = sn; buf ^= 1;
    }
}

extern "C" void kernel_launch(void* const* d_in, const int* in_sizes, int n_in,
                              void* d_out, int out_size, void* d_ws, size_t ws_size,
                              hipStream_t stream) {
    const float* fi = (const float*)d_in[0];
    const float* fj = (const float*)d_in[1];
    const float* w1 = (const float*)d_in[2];
    const float* b1 = (const float*)d_in[3];
    const float* w2 = (const float*)d_in[4];
    const float* b2 = (const float*)d_in[5];
    float* out = (float*)d_out;

    v3_kernel<<<(NSITES + 63) / 64, 256, 0, stream>>>(fi, w1, b1, w2, b2, out);
    edge_kernel<<<256, 512, 0, stream>>>(fj, w2, out);
}